// Round 11
// baseline (246.063 us; speedup 1.0000x reference)
//
#include <hip/hip_runtime.h>
#include <hip/hip_bf16.h>

// Renderer vertex-normals rev11. Math FROZEN from rev8 (passing, absmax = 1 bf16 ulp):
//   cross: c_i = fmaf(a_p, b_q, -pinned(a_q*b_p))  (uniform LHS fusion)
//   norms: (x*x + y*y) + z*z, sqrtf, fmaxf(n,1e-12f), IEEE '/'
//   vertex sum: c = 0..5 sequential
// Rev11 = rev10 XCD partitioning + NON-TEMPORAL streams (layout only):
//   R10 vertex still fetched 275 MB vs ~92 compulsory: vti/vtw reads and
//   out/fn write streams evict the 2.08 MB fn gather table from the 4 MB
//   per-XCD L2. All zero-reuse traffic now uses nontemporal load/store so
//   L2 holds only the gather tables. Face pass restructured to load indices
//   once and loop its XCD's batches (in-phase pts4 sweep).
// bs=32, V=65536, F=130050, C=6.

#define XCDS 8

typedef float f4v __attribute__((ext_vector_type(4)));
typedef int   i2v __attribute__((ext_vector_type(2)));
typedef float f2v __attribute__((ext_vector_type(2)));

__device__ __forceinline__ int2 nt_load_int2(const int* p) {
  i2v t = __builtin_nontemporal_load((const i2v*)p);
  return make_int2(t.x, t.y);
}
__device__ __forceinline__ float2 nt_load_float2(const float* p) {
  f2v t = __builtin_nontemporal_load((const f2v*)p);
  return make_float2(t.x, t.y);
}
__device__ __forceinline__ void nt_store_float4(float4* p, float x, float y,
                                                float z, float w) {
  f4v t; t.x = x; t.y = y; t.z = z; t.w = w;
  __builtin_nontemporal_store(t, (f4v*)p);
}

__device__ __forceinline__ float mulf_pin(float a, float b) {
  float t = a * b;
  asm("" : "+v"(t));   // pin: separately-rounded f32 product, cannot re-fuse
  return t;
}

__device__ __forceinline__ float3 cross_lhs(float ax, float ay, float az,
                                            float bx, float by, float bz) {
  float cx = __builtin_fmaf(ay, bz, -mulf_pin(az, by));
  float cy = __builtin_fmaf(az, bx, -mulf_pin(ax, bz));
  float cz = __builtin_fmaf(ax, by, -mulf_pin(ay, bx));
  return make_float3(cx, cy, cz);
}

// ---------------- Kernel A: pack points into float4 (all-stream, nt) -------
__global__ __launch_bounds__(256) void rend11_pack(
    const float* __restrict__ points,   // (bs, 3, V)
    float4*      __restrict__ pts4,     // (bs, V)
    int V) {
  int v = blockIdx.x * blockDim.x + threadIdx.x;
  int b = blockIdx.y;
  const float* pb = points + (size_t)b * 3 * V;
  float x = __builtin_nontemporal_load(pb + v);
  float y = __builtin_nontemporal_load(pb + V + v);
  float z = __builtin_nontemporal_load(pb + 2 * V + v);
  nt_store_float4(&pts4[(size_t)b * V + v], x, y, z, 0.0f);
}

// ---------------- Kernel B: face normals ------------------------------------
// grid.x = XCDS * fpb. Thread loads its 3 indices once (nt), loops its XCD's
// bpx batches; pts4 tables (1.05 MB) swept in phase; fn written nt (stream).
__global__ __launch_bounds__(256) void rend11_face(
    const float4* __restrict__ pts4,    // (bs, V)
    const int*    __restrict__ faces,   // (F, 3)
    float4*       __restrict__ fnorm,   // (bs, F)
    int F, int V, int bpx) {
  int xcd = blockIdx.x % XCDS;
  int seq = blockIdx.x / XCDS;
  int f   = seq * 256 + threadIdx.x;
  if (f >= F) return;

  int i0 = __builtin_nontemporal_load(faces + 3 * f + 0);
  int i1 = __builtin_nontemporal_load(faces + 3 * f + 1);
  int i2 = __builtin_nontemporal_load(faces + 3 * f + 2);

  for (int bl = 0; bl < bpx; ++bl) {
    int b = xcd * bpx + bl;
    const float4* P = pts4 + (size_t)b * V;
    float4 p0 = P[i0];          // cached gathers: table stays L2-hot
    float4 p1 = P[i1];
    float4 p2 = P[i2];

    float ax = p1.x - p0.x, ay = p1.y - p0.y, az = p1.z - p0.z;
    float bx = p2.x - p0.x, by = p2.y - p0.y, bz = p2.z - p0.z;

    float3 c = cross_lhs(ax, ay, az, bx, by, bz);

    float n = sqrtf((c.x * c.x + c.y * c.y) + c.z * c.z);
    float d = fmaxf(n, 1e-12f);

    nt_store_float4(&fnorm[(size_t)b * F + f], c.x / d, c.y / d, c.z / d, 0.0f);
  }
}

// ---------------- Kernel C: vertex normals ----------------------------------
// grid.x = XCDS * vpb. vti/vtw nt-loaded once; fn gathers cached; out nt.
__global__ __launch_bounds__(256) void rend11_vertex(
    const float4* __restrict__ fnorm,   // (bs, F)
    const int*    __restrict__ vti,     // (V, 6)
    const float*  __restrict__ vtw,     // (V, 6)
    float*        __restrict__ out,     // (bs, V, 3)
    int F, int V, int bpx) {
  int xcd = blockIdx.x % XCDS;
  int seq = blockIdx.x / XCDS;
  int v   = seq * 256 + threadIdx.x;
  if (v >= V) return;

  int2   t01 = nt_load_int2(vti + (size_t)v * 6 + 0);
  int2   t23 = nt_load_int2(vti + (size_t)v * 6 + 2);
  int2   t45 = nt_load_int2(vti + (size_t)v * 6 + 4);
  float2 w01 = nt_load_float2(vtw + (size_t)v * 6 + 0);
  float2 w23 = nt_load_float2(vtw + (size_t)v * 6 + 2);
  float2 w45 = nt_load_float2(vtw + (size_t)v * 6 + 4);
  int   idx[6] = {t01.x, t01.y, t23.x, t23.y, t45.x, t45.y};
  float wgt[6] = {w01.x, w01.y, w23.x, w23.y, w45.x, w45.y};

  for (int bl = 0; bl < bpx; ++bl) {
    int b = xcd * bpx + bl;
    const float4* FN = fnorm + (size_t)b * F;

    float sx = 0.f, sy = 0.f, sz = 0.f;
#pragma unroll
    for (int c = 0; c < 6; ++c) {          // sequential c-order (frozen)
      float4 nr = FN[idx[c]];              // cached gathers
      sx += nr.x * wgt[c];
      sy += nr.y * wgt[c];
      sz += nr.z * wgt[c];
    }

    float n = sqrtf((sx * sx + sy * sy) + sz * sz);
    float d = fmaxf(n, 1e-12f);

    size_t o = ((size_t)b * V + v) * 3;
    __builtin_nontemporal_store(sx / d, out + o + 0);
    __builtin_nontemporal_store(sy / d, out + o + 1);
    __builtin_nontemporal_store(sz / d, out + o + 2);
  }
}

// ================= Fallback path (rev8, proven): ===========================
__global__ __launch_bounds__(256) void rend11_face_fb(
    const float* __restrict__ points,
    const int*   __restrict__ faces,
    float4*      __restrict__ fnorm,
    int F, int V) {
  int f = blockIdx.x * blockDim.x + threadIdx.x;
  int b = blockIdx.y;
  if (f >= F) return;

  int i0 = faces[3 * f + 0];
  int i1 = faces[3 * f + 1];
  int i2 = faces[3 * f + 2];

  const float* pb = points + (size_t)b * 3 * V;
  float ax = pb[i1] - pb[i0], ay = pb[V + i1] - pb[V + i0], az = pb[2 * V + i1] - pb[2 * V + i0];
  float bx = pb[i2] - pb[i0], by = pb[V + i2] - pb[V + i0], bz = pb[2 * V + i2] - pb[2 * V + i0];

  float3 c = cross_lhs(ax, ay, az, bx, by, bz);

  float n = sqrtf((c.x * c.x + c.y * c.y) + c.z * c.z);
  float d = fmaxf(n, 1e-12f);

  fnorm[(size_t)b * F + f] = make_float4(c.x / d, c.y / d, c.z / d, 0.0f);
}

__global__ __launch_bounds__(256) void rend11_vertex_fb(
    const float4* __restrict__ fnorm,
    const int*    __restrict__ vti,
    const float*  __restrict__ vtw,
    float*        __restrict__ out,
    int F, int V) {
  int v = blockIdx.x * blockDim.x + threadIdx.x;
  int b = blockIdx.y;
  if (v >= V) return;

  const float4* fb = fnorm + (size_t)b * F;
  float sx = 0.f, sy = 0.f, sz = 0.f;
#pragma unroll
  for (int c = 0; c < 6; ++c) {
    int    idx = vti[v * 6 + c];
    float  w   = vtw[v * 6 + c];
    float4 nr  = fb[idx];
    sx += nr.x * w;
    sy += nr.y * w;
    sz += nr.z * w;
  }
  float n = sqrtf((sx * sx + sy * sy) + sz * sz);
  float d = fmaxf(n, 1e-12f);
  size_t o = ((size_t)b * V + v) * 3;
  out[o + 0] = sx / d;
  out[o + 1] = sy / d;
  out[o + 2] = sz / d;
}

extern "C" void kernel_launch(void* const* d_in, const int* in_sizes, int n_in,
                              void* d_out, int out_size, void* d_ws, size_t ws_size,
                              hipStream_t stream) {
  const float* points = (const float*)d_in[0];
  const int*   faces  = (const int*)d_in[1];
  const int*   vti    = (const int*)d_in[2];
  const float* vtw    = (const float*)d_in[3];
  float*       out    = (float*)d_out;

  const int F  = in_sizes[1] / 3;                       // 130050
  const int V  = in_sizes[2] / 6;                       // 65536
  const int bs = (int)(in_sizes[0] / (3 * (size_t)V));  // 32

  const size_t pts4_bytes = (size_t)bs * V * sizeof(float4);  // 33.6 MB
  const size_t fn_bytes   = (size_t)bs * F * sizeof(float4);  // 66.6 MB

  const bool fast_ok = (ws_size >= pts4_bytes + fn_bytes) &&
                       (bs % XCDS == 0) && (V % 256 == 0);

  if (fast_ok) {
    float4* pts4  = (float4*)d_ws;
    float4* fnorm = (float4*)((char*)d_ws + pts4_bytes);
    const int bpx = bs / XCDS;                 // 4 batches per XCD
    const int fpb = (F + 255) / 256;           // 509 face-blocks per batch
    const int vpb = V / 256;                   // 256 vertex-blocks

    rend11_pack<<<dim3(V / 256, bs), dim3(256), 0, stream>>>(points, pts4, V);
    rend11_face<<<dim3(XCDS * fpb), dim3(256), 0, stream>>>(
        pts4, faces, fnorm, F, V, bpx);
    rend11_vertex<<<dim3(XCDS * vpb), dim3(256), 0, stream>>>(
        fnorm, vti, vtw, out, F, V, bpx);
  } else if (ws_size >= fn_bytes) {  // rev8 fallback
    float4* fnorm = (float4*)d_ws;
    rend11_face_fb<<<dim3((F + 255) / 256, bs), dim3(256), 0, stream>>>(
        points, faces, fnorm, F, V);
    rend11_vertex_fb<<<dim3((V + 255) / 256, bs), dim3(256), 0, stream>>>(
        fnorm, vti, vtw, out, F, V);
  }
}